// Round 5
// baseline (403.093 us; speedup 1.0000x reference)
//
#include <hip/hip_runtime.h>
#include <stdint.h>

#define BN_EPS 1e-5f
#define BW    256        // nodes per bucket
#define BSH   8          // log2(BW)
#define SLACK 10240      // entries reserved per bucket (mean ~8184, huge margin)
#define TILE  4096       // edges per binning block

static __device__ __forceinline__ uint32_t bf16bits(float f){
  uint32_t u = __float_as_uint(f);
  return (u + 0x7fffu + ((u>>16)&1u)) >> 16;
}
static __device__ __forceinline__ float bf16tof(uint32_t us){
  return __uint_as_float(us<<16);
}
static __device__ __forceinline__ void acc8(float* acc, uint4 v){
  acc[0]+=bf16tof(v.x&0xFFFFu); acc[1]+=bf16tof(v.x>>16);
  acc[2]+=bf16tof(v.y&0xFFFFu); acc[3]+=bf16tof(v.y>>16);
  acc[4]+=bf16tof(v.z&0xFFFFu); acc[5]+=bf16tof(v.z>>16);
  acc[6]+=bf16tof(v.w&0xFFFFu); acc[7]+=bf16tof(v.w>>16);
}

// ---------- weight precompute + breakpoint sort ----------
// a1/b1v: fold Linear(1,256)+BN1 -> per-channel affine of s
// bp[c] = -b1v/a1 (ReLU breakpoint); rank-sort 256 bps -> sorted_p, perm
__global__ __launch_bounds__(256) void prep_small(const float* __restrict__ w1a, const float* __restrict__ b1a,
                           const float* __restrict__ g1,  const float* __restrict__ be1,
                           const float* __restrict__ m1,  const float* __restrict__ v1,
                           const float* __restrict__ b1b, const float* __restrict__ w2a,
                           const float* __restrict__ b2a, const float* __restrict__ g2,
                           const float* __restrict__ be2, const float* __restrict__ m2,
                           const float* __restrict__ v2,
                           float* __restrict__ a1, float* __restrict__ b1v,
                           float* __restrict__ c12, float* __restrict__ A2, float* __restrict__ B2,
                           float* __restrict__ sorted_p, int* __restrict__ perm){
  __shared__ float bpl[256];
  int c = threadIdx.x;
  float s1 = g1[c] * rsqrtf(v1[c] + BN_EPS);
  float av = w1a[c] * s1;
  float bv = (b1a[c] - m1[c]) * s1 + be1[c];
  a1[c]  = av;
  b1v[c] = bv;
  if (c < 64){
    float acc = 0.f;
    for (int d = 0; d < 128; ++d) acc = fmaf(b1b[d], w2a[d*64 + c], acc);
    c12[c] = acc;
    float s2 = g2[c] * rsqrtf(v2[c] + BN_EPS);
    A2[c] = s2;
    B2[c] = (b2a[c] - m2[c]) * s2 + be2[c];
  }
  // breakpoint (clamped to finite range; a==0 -> never crossed)
  float bp;
  if (av == 0.f) bp = 1e30f;
  else bp = fminf(fmaxf(-bv/av, -1e30f), 1e30f);
  bpl[c] = bp;
  __syncthreads();
  int rank = 0;
  for (int j = 0; j < 256; ++j){
    float bj = bpl[j];
    rank += (bj < bp) || (bj == bp && j < c);
  }
  sorted_p[rank] = bp;
  perm[rank] = c;
}

// W12 = w1b[256,128] @ w2a[128,64]
__global__ void prep_w12(const float* __restrict__ w1b, const float* __restrict__ w2a,
                         float* __restrict__ W12){
  int idx = blockIdx.x*256 + threadIdx.x;   // 16384 threads
  int c = idx >> 6, k = idx & 63;
  float acc = 0.f;
  for (int d = 0; d < 128; ++d) acc = fmaf(w1b[c*128 + d], w2a[d*64 + k], acc);
  W12[idx] = acc;
}

// ---------- build piecewise-linear table AB[257][128] ----------
// interval m (between sorted breakpoints m-1 and m): t[k] = A_k*s + B_k
// one block, 64 threads (thread = output channel k); incremental over crossings
__global__ __launch_bounds__(64) void build_ab(const float* __restrict__ a1, const float* __restrict__ b1v,
                                               const float* __restrict__ W12, const float* __restrict__ c12,
                                               const int* __restrict__ perm, float* __restrict__ AB){
  int k = threadIdx.x;
  float A = 0.f, B = c12[k];
  // interval 0 (s below all breakpoints): active = {a<0} U {a==0 && b>0}
  for (int c = 0; c < 256; ++c){
    float a = a1[c], b = b1v[c];
    bool act = (a < 0.f) || (a == 0.f && b > 0.f);
    float w = W12[c*64 + k];
    if (act){ A = fmaf(a, w, A); B = fmaf(b, w, B); }
  }
  AB[k] = A; AB[64 + k] = B;
  for (int m = 1; m <= 256; ++m){
    int g = perm[m-1];
    float a = a1[g], b = b1v[g];
    float w = W12[g*64 + k];
    if (a > 0.f){ A = fmaf(a, w, A); B = fmaf(b, w, B); }          // becomes active
    else if (a < 0.f){ A = fmaf(-a, w, A); B = fmaf(-b, w, B); }   // becomes inactive
    AB[m*128 + k] = A; AB[m*128 + 64 + k] = B;
  }
}

__global__ void init_gpos(int* __restrict__ gpos, int nb){
  int i = blockIdx.x*256 + threadIdx.x;
  if (i < nb) gpos[i] = i * SLACK;
}

// ---------- pass 1: bin edges by dst bucket (block-local counting sort) ----------
__global__ __launch_bounds__(512) void bin_edges(const int* __restrict__ ei, int* __restrict__ gpos,
                                                 uint32_t* __restrict__ binned, int E, int nb){
  __shared__ int hist[512];
  __shared__ int sc[512];
  __shared__ int cur[512];
  __shared__ int gbase[512];
  __shared__ uint32_t staged[TILE];
  __shared__ uint16_t bof[TILE];
  int t = threadIdx.x;
  int base = blockIdx.x * TILE;
  hist[t] = 0;
  __syncthreads();
  #pragma unroll
  for (int k = 0; k < TILE/512; ++k){
    int e = base + t + k*512;
    if (e < E) atomicAdd(&hist[ei[E + e] >> BSH], 1);
  }
  __syncthreads();
  int mycnt = hist[t];
  sc[t] = mycnt;
  __syncthreads();
  for (int off = 1; off < 512; off <<= 1){
    int v = (t >= off) ? sc[t-off] : 0;
    __syncthreads();
    sc[t] += v;
    __syncthreads();
  }
  int excl = sc[t] - mycnt;
  hist[t] = excl;
  cur[t]  = excl;
  if (t < nb && mycnt > 0) gbase[t] = atomicAdd(&gpos[t], mycnt);
  __syncthreads();
  #pragma unroll
  for (int k = 0; k < TILE/512; ++k){
    int e = base + t + k*512;
    if (e < E){
      int d = ei[E + e];
      int s = ei[e];
      int b = d >> BSH;
      int slot = atomicAdd(&cur[b], 1);
      staged[slot] = ((uint32_t)(d & (BW-1)) << 17) | (uint32_t)s;
      bof[slot] = (uint16_t)b;
    }
  }
  __syncthreads();
  int tileCount = min(TILE, E - base);
  for (int i = t; i < tileCount; i += 512){
    int b = bof[i];
    binned[gbase[b] + (i - hist[b])] = staged[i];
  }
}

// ---------- exclusive scan of bucket counts -> global col base ----------
__global__ __launch_bounds__(512) void scan_buckets(const int* __restrict__ gpos, int* __restrict__ bucket_base,
                                                    int* __restrict__ rowstart, int nb, int n, int E){
  __shared__ int sm[512];
  int t = threadIdx.x;
  int c = (t < nb) ? (gpos[t] - t*SLACK) : 0;
  sm[t] = c; __syncthreads();
  for (int off = 1; off < 512; off <<= 1){
    int v = (t >= off) ? sm[t-off] : 0;
    __syncthreads();
    sm[t] += v;
    __syncthreads();
  }
  if (t < nb) bucket_base[t] = sm[t] - c;
  if (t == 0) rowstart[n] = E;
}

// ---------- pass 2: within-bucket sort by dst -> CSR (col + rowstart) ----------
__global__ __launch_bounds__(512) void sort_bucket(const uint32_t* __restrict__ binned, const int* __restrict__ gpos,
                                                   const int* __restrict__ bucket_base, int* __restrict__ rowstart,
                                                   int* __restrict__ col, int n){
  __shared__ int hist[BW];
  __shared__ int sc[BW];
  __shared__ int cur[BW];
  int b = blockIdx.x, t = threadIdx.x;
  int cnt = gpos[b] - b*SLACK;
  const uint32_t* src = binned + (size_t)b*SLACK;
  if (t < BW) hist[t] = 0;
  __syncthreads();
  for (int i = t; i < cnt; i += 512) atomicAdd(&hist[src[i] >> 17], 1);
  __syncthreads();
  if (t < BW) sc[t] = hist[t];
  __syncthreads();
  for (int off = 1; off < BW; off <<= 1){
    int v = (t < BW && t >= off) ? sc[t-off] : 0;
    __syncthreads();
    if (t < BW) sc[t] += v;
    __syncthreads();
  }
  int base = bucket_base[b];
  if (t < BW){
    int e = sc[t] - hist[t];
    cur[t] = base + e;
    int node = (b << BSH) + t;
    if (node < n) rowstart[node] = base + e;
  }
  __syncthreads();
  for (int i = t; i < cnt; i += 512){
    uint32_t e = src[i];
    int p = atomicAdd(&cur[e >> 17], 1);
    col[p] = (int)(e & 0x1FFFFu);
  }
}

// ---------- GIN1 via piecewise-linear table: 4 lanes/node ----------
// s = x_i + sum_j x_j ; m = upper_bound(sorted_p, s) ; t[k] = AB[m].A[k]*s + AB[m].B[k]
__global__ __launch_bounds__(256) void gin1_pwl(const float* __restrict__ x,
    const int* __restrict__ rowstart, const int* __restrict__ col,
    const float* __restrict__ sorted_p, const float* __restrict__ AB,
    unsigned short* __restrict__ t, int n){
  __shared__ float sp[256];
  sp[threadIdx.x] = sorted_p[threadIdx.x];
  __syncthreads();
  int tid = blockIdx.x*256 + threadIdx.x;
  int node = tid >> 2, sub = tid & 3;       // 4 lanes per node, lane=16 channels
  if (node >= n) return;
  int beg = rowstart[node], end = rowstart[node+1];
  float s = 0.f;
  for (int j = beg + sub; j < end; j += 4) s += x[col[j]];
  s += __shfl_xor(s, 1);
  s += __shfl_xor(s, 2);
  s += x[node];
  // binary search: m = count(sorted_p <= s), 8 steps in LDS
  int lo = 0, hi = 256;
  while (lo < hi){
    int mid = (lo + hi) >> 1;
    if (sp[mid] <= s) lo = mid + 1; else hi = mid;
  }
  const float* ab = AB + lo*128 + sub*16;
  const float4* Ap = reinterpret_cast<const float4*>(ab);
  const float4* Bp = reinterpret_cast<const float4*>(ab + 64);
  uint4 o0, o1;
  {
    float4 A0 = Ap[0], A1 = Ap[1], B0 = Bp[0], B1 = Bp[1];
    o0.x = bf16bits(fmaf(A0.x,s,B0.x)) | (bf16bits(fmaf(A0.y,s,B0.y))<<16);
    o0.y = bf16bits(fmaf(A0.z,s,B0.z)) | (bf16bits(fmaf(A0.w,s,B0.w))<<16);
    o0.z = bf16bits(fmaf(A1.x,s,B1.x)) | (bf16bits(fmaf(A1.y,s,B1.y))<<16);
    o0.w = bf16bits(fmaf(A1.z,s,B1.z)) | (bf16bits(fmaf(A1.w,s,B1.w))<<16);
  }
  {
    float4 A2v = Ap[2], A3 = Ap[3], B2v = Bp[2], B3 = Bp[3];
    o1.x = bf16bits(fmaf(A2v.x,s,B2v.x)) | (bf16bits(fmaf(A2v.y,s,B2v.y))<<16);
    o1.y = bf16bits(fmaf(A2v.z,s,B2v.z)) | (bf16bits(fmaf(A2v.w,s,B2v.w))<<16);
    o1.z = bf16bits(fmaf(A3.x,s,B3.x)) | (bf16bits(fmaf(A3.y,s,B3.y))<<16);
    o1.w = bf16bits(fmaf(A3.z,s,B3.z)) | (bf16bits(fmaf(A3.w,s,B3.w))<<16);
  }
  uint4* dst = reinterpret_cast<uint4*>(t + (size_t)node*64 + sub*16);
  dst[0] = o0;
  dst[1] = o1;
}

// ---------- GIN2 aggregation: 8 nodes/wave, 8 lanes/node, register accum ----------
__global__ __launch_bounds__(256) void agg8(const int* __restrict__ rowstart, const int* __restrict__ col,
                                            const unsigned short* __restrict__ t,
                                            const float* __restrict__ A2, const float* __restrict__ B2,
                                            unsigned short* __restrict__ r2, int n){
  int tid = blockIdx.x*256 + threadIdx.x;
  int lane = threadIdx.x & 63;
  int node = ((tid >> 6) << 3) + (lane >> 3);
  int slot = lane & 7;                      // 8-channel slot within the row
  bool valid = node < n;
  int beg = valid ? rowstart[node] : 0;
  int end = valid ? rowstart[node+1] : 0;
  float acc[8];
  {  // self row
    const uint4* trow = reinterpret_cast<const uint4*>(t + ((size_t)(valid ? node : 0))*64 + slot*8);
    uint4 v = *trow;
    acc[0]=bf16tof(v.x&0xFFFFu); acc[1]=bf16tof(v.x>>16);
    acc[2]=bf16tof(v.y&0xFFFFu); acc[3]=bf16tof(v.y>>16);
    acc[4]=bf16tof(v.z&0xFFFFu); acc[5]=bf16tof(v.z>>16);
    acc[6]=bf16tof(v.w&0xFFFFu); acc[7]=bf16tof(v.w>>16);
    if (!valid){
      #pragma unroll
      for (int q = 0; q < 8; ++q) acc[q] = 0.f;
    }
  }
  for (int j = beg; __any(j < end); j += 2){
    bool a0 = j < end, a1 = j + 1 < end;
    int s0 = a0 ? col[j] : 0;
    int s1 = a1 ? col[j+1] : 0;
    uint4 w0, w1;
    if (a0) w0 = *reinterpret_cast<const uint4*>(t + (size_t)s0*64 + slot*8);
    if (a1) w1 = *reinterpret_cast<const uint4*>(t + (size_t)s1*64 + slot*8);
    if (a0) acc8(acc, w0);
    if (a1) acc8(acc, w1);
  }
  if (valid){
    const float4* Ap = reinterpret_cast<const float4*>(A2 + slot*8);
    const float4* Bp = reinterpret_cast<const float4*>(B2 + slot*8);
    float4 A0 = Ap[0], A1 = Ap[1], B0 = Bp[0], B1 = Bp[1];
    float Av[8] = {A0.x,A0.y,A0.z,A0.w,A1.x,A1.y,A1.z,A1.w};
    float Bv[8] = {B0.x,B0.y,B0.z,B0.w,B1.x,B1.y,B1.z,B1.w};
    float r[8];
    #pragma unroll
    for (int q = 0; q < 8; ++q) r[q] = fmaxf(fmaf(acc[q], Av[q], Bv[q]), 0.f);
    uint4 o;
    o.x = bf16bits(r[0]) | (bf16bits(r[1])<<16);
    o.y = bf16bits(r[2]) | (bf16bits(r[3])<<16);
    o.z = bf16bits(r[4]) | (bf16bits(r[5])<<16);
    o.w = bf16bits(r[6]) | (bf16bits(r[7])<<16);
    *reinterpret_cast<uint4*>(r2 + (size_t)node*64 + slot*8) = o;
  }
}

// ---------- Linear(64,64) + head + log_softmax ----------
__global__ __launch_bounds__(256) void head_kernel(const unsigned short* __restrict__ r2,
    const float* __restrict__ w2b, const float* __restrict__ b2b,
    const float* __restrict__ wl1, const float* __restrict__ bl1,
    const float* __restrict__ wl2, const float* __restrict__ bl2,
    float* __restrict__ out, int n){
  int i = blockIdx.x*256 + threadIdx.x;
  if (i >= n) return;
  float hacc[64];
  #pragma unroll
  for (int k = 0; k < 64; ++k) hacc[k] = b2b[k];
  const uint4* rr = reinterpret_cast<const uint4*>(r2 + (size_t)i*64);
  for (int q = 0; q < 8; ++q){
    uint4 rv = rr[q];
    uint32_t wv[4] = {rv.x, rv.y, rv.z, rv.w};
    #pragma unroll
    for (int e2 = 0; e2 < 4; ++e2){
      float rlo = bf16tof(wv[e2] & 0xFFFFu);
      float rhi = bf16tof(wv[e2] >> 16);
      const float* wr0 = w2b + (q*8 + e2*2)*64;   // wave-uniform -> s_load
      #pragma unroll
      for (int k = 0; k < 64; ++k) hacc[k] = fmaf(rlo, wr0[k], hacc[k]);
      const float* wr1 = wr0 + 64;
      #pragma unroll
      for (int k = 0; k < 64; ++k) hacc[k] = fmaf(rhi, wr1[k], hacc[k]);
    }
  }
  float z[16];
  #pragma unroll
  for (int jj = 0; jj < 16; ++jj) z[jj] = bl1[jj];
  #pragma unroll
  for (int k = 0; k < 64; ++k){
    float hk = hacc[k];
    const float* wr = wl1 + k*16;
    #pragma unroll
    for (int jj = 0; jj < 16; ++jj) z[jj] = fmaf(hk, wr[jj], z[jj]);
  }
  float lg[6];
  #pragma unroll
  for (int l = 0; l < 6; ++l) lg[l] = bl2[l];
  #pragma unroll
  for (int jj = 0; jj < 16; ++jj){
    float zj = fmaxf(z[jj], 0.f);
    const float* wr = wl2 + jj*6;
    #pragma unroll
    for (int l = 0; l < 6; ++l) lg[l] = fmaf(zj, wr[l], lg[l]);
  }
  float mx = lg[0];
  #pragma unroll
  for (int l = 1; l < 6; ++l) mx = fmaxf(mx, lg[l]);
  float sum = 0.f;
  #pragma unroll
  for (int l = 0; l < 6; ++l) sum += expf(lg[l] - mx);
  float lse = mx + logf(sum);
  float* op = out + (size_t)i*6;
  #pragma unroll
  for (int l = 0; l < 6; ++l) op[l] = lg[l] - lse;
}

extern "C" void kernel_launch(void* const* d_in, const int* in_sizes, int n_in,
                              void* d_out, int out_size, void* d_ws, size_t ws_size,
                              hipStream_t stream){
  const float* x   = (const float*)d_in[0];
  const int*   ei  = (const int*)d_in[1];
  const float* w1a = (const float*)d_in[2];
  const float* b1a = (const float*)d_in[3];
  const float* g1  = (const float*)d_in[4];
  const float* be1 = (const float*)d_in[5];
  const float* m1  = (const float*)d_in[6];
  const float* v1  = (const float*)d_in[7];
  const float* w1b = (const float*)d_in[8];
  const float* b1b = (const float*)d_in[9];
  const float* w2a = (const float*)d_in[10];
  const float* b2a = (const float*)d_in[11];
  const float* g2  = (const float*)d_in[12];
  const float* be2 = (const float*)d_in[13];
  const float* m2  = (const float*)d_in[14];
  const float* v2  = (const float*)d_in[15];
  const float* w2b = (const float*)d_in[16];
  const float* b2b = (const float*)d_in[17];
  const float* wl1 = (const float*)d_in[18];
  const float* bl1 = (const float*)d_in[19];
  const float* wl2 = (const float*)d_in[20];
  const float* bl2 = (const float*)d_in[21];
  float* out = (float*)d_out;
  int n = in_sizes[0];        // N
  int E = in_sizes[1] / 2;    // edges
  int nb = (n + BW - 1) >> BSH;

  char* ws = (char*)d_ws;
  size_t off = 0;
  auto carve = [&](size_t bytes)->char*{ char* p = ws + off; off += (bytes + 255) & ~(size_t)255; return p; };
  float* a1   = (float*)carve(256*4);
  float* b1v  = (float*)carve(256*4);
  float* c12  = (float*)carve(64*4);
  float* A2   = (float*)carve(64*4);
  float* B2   = (float*)carve(64*4);
  float* W12  = (float*)carve(16384*4);
  float* sorted_p = (float*)carve(256*4);
  int*   perm = (int*)carve(256*4);
  float* AB   = (float*)carve(257*128*4);
  int* gpos   = (int*)carve((size_t)nb*4);
  int* bucket_base = (int*)carve((size_t)nb*4);
  int* rowstart = (int*)carve((size_t)(n+1)*4);
  int* col    = (int*)carve((size_t)E*4);
  uint32_t* binned = (uint32_t*)carve((size_t)nb*SLACK*4);
  unsigned short* t  = (unsigned short*)binned;   // alias: binned dead after sort_bucket
  unsigned short* r2 = (unsigned short*)carve((size_t)n*64*2);

  int nblk = (n + 255) / 256;
  prep_small<<<1, 256, 0, stream>>>(w1a,b1a,g1,be1,m1,v1,b1b,w2a,b2a,g2,be2,m2,v2,
                                    a1,b1v,c12,A2,B2,sorted_p,perm);
  prep_w12<<<64, 256, 0, stream>>>(w1b, w2a, W12);
  build_ab<<<1, 64, 0, stream>>>(a1, b1v, W12, c12, perm, AB);
  init_gpos<<<(nb + 255)/256, 256, 0, stream>>>(gpos, nb);
  bin_edges<<<(E + TILE - 1)/TILE, 512, 0, stream>>>(ei, gpos, binned, E, nb);
  scan_buckets<<<1, 512, 0, stream>>>(gpos, bucket_base, rowstart, nb, n, E);
  sort_bucket<<<nb, 512, 0, stream>>>(binned, gpos, bucket_base, rowstart, col, n);
  gin1_pwl<<<((size_t)n*4 + 255)/256, 256, 0, stream>>>(x, rowstart, col, sorted_p, AB, t, n);
  agg8<<<(n + 31)/32, 256, 0, stream>>>(rowstart, col, t, A2, B2, r2, n);
  head_kernel<<<nblk, 256, 0, stream>>>(r2, w2b, b2b, wl1, bl1, wl2, bl2, out, n);
}

// Round 8
// 309.353 us; speedup vs baseline: 1.3030x; 1.3030x over previous
//
#include <hip/hip_runtime.h>
#include <stdint.h>

#define BN_EPS 1e-5f
#define BW    256        // nodes per bucket
#define BSH   8          // log2(BW)
#define SLACK 10240      // entries reserved per bucket (mean ~8184, huge margin)
#define TILE  4096       // edges per binning block

static __device__ __forceinline__ uint32_t bf16bits(float f){
  uint32_t u = __float_as_uint(f);
  return (u + 0x7fffu + ((u>>16)&1u)) >> 16;
}
static __device__ __forceinline__ float bf16tof(uint32_t us){
  return __uint_as_float(us<<16);
}
static __device__ __forceinline__ void acc8(float* acc, uint4 v){
  acc[0]+=bf16tof(v.x&0xFFFFu); acc[1]+=bf16tof(v.x>>16);
  acc[2]+=bf16tof(v.y&0xFFFFu); acc[3]+=bf16tof(v.y>>16);
  acc[4]+=bf16tof(v.z&0xFFFFu); acc[5]+=bf16tof(v.z>>16);
  acc[6]+=bf16tof(v.w&0xFFFFu); acc[7]+=bf16tof(v.w>>16);
}

// ---------- weight precompute + breakpoint sort ----------
__global__ __launch_bounds__(256) void prep_small(const float* __restrict__ w1a, const float* __restrict__ b1a,
                           const float* __restrict__ g1,  const float* __restrict__ be1,
                           const float* __restrict__ m1,  const float* __restrict__ v1,
                           const float* __restrict__ b1b, const float* __restrict__ w2a,
                           const float* __restrict__ b2a, const float* __restrict__ g2,
                           const float* __restrict__ be2, const float* __restrict__ m2,
                           const float* __restrict__ v2,
                           float* __restrict__ a1, float* __restrict__ b1v,
                           float* __restrict__ c12, float* __restrict__ A2, float* __restrict__ B2,
                           float* __restrict__ sorted_p, int* __restrict__ perm){
  __shared__ float bpl[256];
  int c = threadIdx.x;
  float s1 = g1[c] * rsqrtf(v1[c] + BN_EPS);
  float av = w1a[c] * s1;
  float bv = (b1a[c] - m1[c]) * s1 + be1[c];
  a1[c]  = av;
  b1v[c] = bv;
  if (c < 64){
    float acc = 0.f;
    for (int d = 0; d < 128; ++d) acc = fmaf(b1b[d], w2a[d*64 + c], acc);
    c12[c] = acc;
    float s2 = g2[c] * rsqrtf(v2[c] + BN_EPS);
    A2[c] = s2;
    B2[c] = (b2a[c] - m2[c]) * s2 + be2[c];
  }
  float bp;
  if (av == 0.f) bp = 1e30f;
  else bp = fminf(fmaxf(-bv/av, -1e30f), 1e30f);
  bpl[c] = bp;
  __syncthreads();
  int rank = 0;
  for (int j = 0; j < 256; ++j){
    float bj = bpl[j];
    rank += (bj < bp) || (bj == bp && j < c);
  }
  sorted_p[rank] = bp;
  perm[rank] = c;
}

// W12 = w1b[256,128] @ w2a[128,64]
__global__ void prep_w12(const float* __restrict__ w1b, const float* __restrict__ w2a,
                         float* __restrict__ W12){
  int idx = blockIdx.x*256 + threadIdx.x;   // 16384 threads
  int c = idx >> 6, k = idx & 63;
  float acc = 0.f;
  for (int d = 0; d < 128; ++d) acc = fmaf(w1b[c*128 + d], w2a[d*64 + k], acc);
  W12[idx] = acc;
}

// ---------- build piecewise-linear table AB[257][128] — PARALLEL ----------
// block = output column (0..63: A_k, 64..127: B_k); thread = crossing index.
// AB[m][col] = base[col] + sum_{j<=m} delta_j[col]  (block reduce + block scan)
// NOTE: B-columns' base must include c12[k] (round-6 bug: it was dropped).
__global__ __launch_bounds__(256) void build_ab_par(const float* __restrict__ a1, const float* __restrict__ b1v,
                                                    const float* __restrict__ W12, const float* __restrict__ c12,
                                                    const int* __restrict__ perm, float* __restrict__ AB){
  __shared__ float sm[256];
  int col = blockIdx.x;        // 0..127
  int k = col & 63;
  bool isA = col < 64;
  int tm = threadIdx.x;        // 0..255
  // base: interval-0 contribution of channel c=tm (active iff a<0, or a==0 && b>0)
  float a0 = a1[tm], b0 = b1v[tm];
  float w0 = W12[tm*64 + k];
  bool act0 = (a0 < 0.f) || (a0 == 0.f && b0 > 0.f);
  float coeff0 = isA ? a0 : b0;
  sm[tm] = act0 ? coeff0*w0 : 0.f;
  __syncthreads();
  for (int off2 = 128; off2 > 0; off2 >>= 1){
    if (tm < off2) sm[tm] += sm[tm + off2];
    __syncthreads();
  }
  float base = sm[0] + (isA ? 0.f : c12[k]);   // <-- fix: c12 in B base
  __syncthreads();
  // delta at crossing tm+1: channel g=perm[tm]; a>0 -> activates (+), a<0 -> deactivates (-)
  int g = perm[tm];
  float ag = a1[g], bg = b1v[g];
  float wg = W12[g*64 + k];
  float cg = isA ? ag : bg;
  float delta = (ag > 0.f) ? cg*wg : ((ag < 0.f) ? -cg*wg : 0.f);
  sm[tm] = delta;
  __syncthreads();
  for (int off = 1; off < 256; off <<= 1){
    float v = (tm >= off) ? sm[tm-off] : 0.f;
    __syncthreads();
    sm[tm] += v;
    __syncthreads();
  }
  AB[(tm+1)*128 + col] = base + sm[tm];
  if (tm == 0) AB[col] = base;
}

__global__ void init_gpos(int* __restrict__ gpos, int nb){
  int i = blockIdx.x*256 + threadIdx.x;
  if (i < nb) gpos[i] = i * SLACK;
}

// ---------- pass 1: bin edges by dst bucket (block-local counting sort) ----------
__global__ __launch_bounds__(512) void bin_edges(const int* __restrict__ ei, int* __restrict__ gpos,
                                                 uint32_t* __restrict__ binned, int E, int nb){
  __shared__ int hist[512];
  __shared__ int sc[512];
  __shared__ int cur[512];
  __shared__ int gbase[512];
  __shared__ uint32_t staged[TILE];
  __shared__ uint16_t bof[TILE];
  int t = threadIdx.x;
  int base = blockIdx.x * TILE;
  hist[t] = 0;
  __syncthreads();
  #pragma unroll
  for (int k = 0; k < TILE/512; ++k){
    int e = base + t + k*512;
    if (e < E) atomicAdd(&hist[ei[E + e] >> BSH], 1);
  }
  __syncthreads();
  int mycnt = hist[t];
  sc[t] = mycnt;
  __syncthreads();
  for (int off = 1; off < 512; off <<= 1){
    int v = (t >= off) ? sc[t-off] : 0;
    __syncthreads();
    sc[t] += v;
    __syncthreads();
  }
  int excl = sc[t] - mycnt;
  hist[t] = excl;
  cur[t]  = excl;
  if (t < nb && mycnt > 0) gbase[t] = atomicAdd(&gpos[t], mycnt);
  __syncthreads();
  #pragma unroll
  for (int k = 0; k < TILE/512; ++k){
    int e = base + t + k*512;
    if (e < E){
      int d = ei[E + e];
      int s = ei[e];
      int b = d >> BSH;
      int slot = atomicAdd(&cur[b], 1);
      staged[slot] = ((uint32_t)(d & (BW-1)) << 17) | (uint32_t)s;
      bof[slot] = (uint16_t)b;
    }
  }
  __syncthreads();
  int tileCount = min(TILE, E - base);
  for (int i = t; i < tileCount; i += 512){
    int b = bof[i];
    binned[gbase[b] + (i - hist[b])] = staged[i];
  }
}

// ---------- exclusive scan of bucket counts -> global col base ----------
__global__ __launch_bounds__(512) void scan_buckets(const int* __restrict__ gpos, int* __restrict__ bucket_base,
                                                    int* __restrict__ rowstart, int nb, int n, int E){
  __shared__ int sm[512];
  int t = threadIdx.x;
  int c = (t < nb) ? (gpos[t] - t*SLACK) : 0;
  sm[t] = c; __syncthreads();
  for (int off = 1; off < 512; off <<= 1){
    int v = (t >= off) ? sm[t-off] : 0;
    __syncthreads();
    sm[t] += v;
    __syncthreads();
  }
  if (t < nb) bucket_base[t] = sm[t] - c;
  if (t == 0) rowstart[n] = E;
}

// ---------- pass 2: within-bucket sort by dst -> CSR (col + rowstart) ----------
__global__ __launch_bounds__(512) void sort_bucket(const uint32_t* __restrict__ binned, const int* __restrict__ gpos,
                                                   const int* __restrict__ bucket_base, int* __restrict__ rowstart,
                                                   int* __restrict__ col, int n){
  __shared__ int hist[BW];
  __shared__ int sc[BW];
  __shared__ int cur[BW];
  int b = blockIdx.x, t = threadIdx.x;
  int cnt = gpos[b] - b*SLACK;
  const uint32_t* src = binned + (size_t)b*SLACK;
  if (t < BW) hist[t] = 0;
  __syncthreads();
  for (int i = t; i < cnt; i += 512) atomicAdd(&hist[src[i] >> 17], 1);
  __syncthreads();
  if (t < BW) sc[t] = hist[t];
  __syncthreads();
  for (int off = 1; off < BW; off <<= 1){
    int v = (t < BW && t >= off) ? sc[t-off] : 0;
    __syncthreads();
    if (t < BW) sc[t] += v;
    __syncthreads();
  }
  int base = bucket_base[b];
  if (t < BW){
    int e = sc[t] - hist[t];
    cur[t] = base + e;
    int node = (b << BSH) + t;
    if (node < n) rowstart[node] = base + e;
  }
  __syncthreads();
  for (int i = t; i < cnt; i += 512){
    uint32_t e = src[i];
    int p = atomicAdd(&cur[e >> 17], 1);
    col[p] = (int)(e & 0x1FFFFu);
  }
}

// ---------- GIN1 via piecewise-linear table: 4 lanes/node ----------
__global__ __launch_bounds__(256) void gin1_pwl(const float* __restrict__ x,
    const int* __restrict__ rowstart, const int* __restrict__ col,
    const float* __restrict__ sorted_p, const float* __restrict__ AB,
    unsigned short* __restrict__ t, int n){
  __shared__ float sp[256];
  sp[threadIdx.x] = sorted_p[threadIdx.x];
  __syncthreads();
  int tid = blockIdx.x*256 + threadIdx.x;
  int node = tid >> 2, sub = tid & 3;       // 4 lanes per node, lane=16 channels
  if (node >= n) return;
  int beg = rowstart[node], end = rowstart[node+1];
  float s = 0.f;
  for (int j = beg + sub; j < end; j += 4) s += x[col[j]];
  s += __shfl_xor(s, 1);
  s += __shfl_xor(s, 2);
  s += x[node];
  int lo = 0, hi = 256;
  while (lo < hi){
    int mid = (lo + hi) >> 1;
    if (sp[mid] <= s) lo = mid + 1; else hi = mid;
  }
  const float* ab = AB + lo*128 + sub*16;
  const float4* Ap = reinterpret_cast<const float4*>(ab);
  const float4* Bp = reinterpret_cast<const float4*>(ab + 64);
  uint4 o0, o1;
  {
    float4 A0 = Ap[0], A1 = Ap[1], B0 = Bp[0], B1 = Bp[1];
    o0.x = bf16bits(fmaf(A0.x,s,B0.x)) | (bf16bits(fmaf(A0.y,s,B0.y))<<16);
    o0.y = bf16bits(fmaf(A0.z,s,B0.z)) | (bf16bits(fmaf(A0.w,s,B0.w))<<16);
    o0.z = bf16bits(fmaf(A1.x,s,B1.x)) | (bf16bits(fmaf(A1.y,s,B1.y))<<16);
    o0.w = bf16bits(fmaf(A1.z,s,B1.z)) | (bf16bits(fmaf(A1.w,s,B1.w))<<16);
  }
  {
    float4 A2v = Ap[2], A3 = Ap[3], B2v = Bp[2], B3 = Bp[3];
    o1.x = bf16bits(fmaf(A2v.x,s,B2v.x)) | (bf16bits(fmaf(A2v.y,s,B2v.y))<<16);
    o1.y = bf16bits(fmaf(A2v.z,s,B2v.z)) | (bf16bits(fmaf(A2v.w,s,B2v.w))<<16);
    o1.z = bf16bits(fmaf(A3.x,s,B3.x)) | (bf16bits(fmaf(A3.y,s,B3.y))<<16);
    o1.w = bf16bits(fmaf(A3.z,s,B3.z)) | (bf16bits(fmaf(A3.w,s,B3.w))<<16);
  }
  uint4* dst = reinterpret_cast<uint4*>(t + (size_t)node*64 + sub*16);
  dst[0] = o0;
  dst[1] = o1;
}

// ---------- GIN2 aggregation: 8 nodes/wave, 8 lanes/node, register accum ----------
__global__ __launch_bounds__(256) void agg8(const int* __restrict__ rowstart, const int* __restrict__ col,
                                            const unsigned short* __restrict__ t,
                                            const float* __restrict__ A2, const float* __restrict__ B2,
                                            unsigned short* __restrict__ r2, int n){
  int tid = blockIdx.x*256 + threadIdx.x;
  int lane = threadIdx.x & 63;
  int node = ((tid >> 6) << 3) + (lane >> 3);
  int slot = lane & 7;                      // 8-channel slot within the row
  bool valid = node < n;
  int beg = valid ? rowstart[node] : 0;
  int end = valid ? rowstart[node+1] : 0;
  float acc[8];
  {  // self row
    const uint4* trow = reinterpret_cast<const uint4*>(t + ((size_t)(valid ? node : 0))*64 + slot*8);
    uint4 v = *trow;
    acc[0]=bf16tof(v.x&0xFFFFu); acc[1]=bf16tof(v.x>>16);
    acc[2]=bf16tof(v.y&0xFFFFu); acc[3]=bf16tof(v.y>>16);
    acc[4]=bf16tof(v.z&0xFFFFu); acc[5]=bf16tof(v.z>>16);
    acc[6]=bf16tof(v.w&0xFFFFu); acc[7]=bf16tof(v.w>>16);
    if (!valid){
      #pragma unroll
      for (int q = 0; q < 8; ++q) acc[q] = 0.f;
    }
  }
  for (int j = beg; __any(j < end); j += 2){
    bool a0 = j < end, a1 = j + 1 < end;
    int s0 = a0 ? col[j] : 0;
    int s1 = a1 ? col[j+1] : 0;
    uint4 w0, w1;
    if (a0) w0 = *reinterpret_cast<const uint4*>(t + (size_t)s0*64 + slot*8);
    if (a1) w1 = *reinterpret_cast<const uint4*>(t + (size_t)s1*64 + slot*8);
    if (a0) acc8(acc, w0);
    if (a1) acc8(acc, w1);
  }
  if (valid){
    const float4* Ap = reinterpret_cast<const float4*>(A2 + slot*8);
    const float4* Bp = reinterpret_cast<const float4*>(B2 + slot*8);
    float4 A0 = Ap[0], A1 = Ap[1], B0 = Bp[0], B1 = Bp[1];
    float Av[8] = {A0.x,A0.y,A0.z,A0.w,A1.x,A1.y,A1.z,A1.w};
    float Bv[8] = {B0.x,B0.y,B0.z,B0.w,B1.x,B1.y,B1.z,B1.w};
    float r[8];
    #pragma unroll
    for (int q = 0; q < 8; ++q) r[q] = fmaxf(fmaf(acc[q], Av[q], Bv[q]), 0.f);
    uint4 o;
    o.x = bf16bits(r[0]) | (bf16bits(r[1])<<16);
    o.y = bf16bits(r[2]) | (bf16bits(r[3])<<16);
    o.z = bf16bits(r[4]) | (bf16bits(r[5])<<16);
    o.w = bf16bits(r[6]) | (bf16bits(r[7])<<16);
    *reinterpret_cast<uint4*>(r2 + (size_t)node*64 + slot*8) = o;
  }
}

// ---------- Linear(64,64) + head + log_softmax ----------
__global__ __launch_bounds__(256) void head_kernel(const unsigned short* __restrict__ r2,
    const float* __restrict__ w2b, const float* __restrict__ b2b,
    const float* __restrict__ wl1, const float* __restrict__ bl1,
    const float* __restrict__ wl2, const float* __restrict__ bl2,
    float* __restrict__ out, int n){
  int i = blockIdx.x*256 + threadIdx.x;
  if (i >= n) return;
  float hacc[64];
  #pragma unroll
  for (int k = 0; k < 64; ++k) hacc[k] = b2b[k];
  const uint4* rr = reinterpret_cast<const uint4*>(r2 + (size_t)i*64);
  for (int q = 0; q < 8; ++q){
    uint4 rv = rr[q];
    uint32_t wv[4] = {rv.x, rv.y, rv.z, rv.w};
    #pragma unroll
    for (int e2 = 0; e2 < 4; ++e2){
      float rlo = bf16tof(wv[e2] & 0xFFFFu);
      float rhi = bf16tof(wv[e2] >> 16);
      const float* wr0 = w2b + (q*8 + e2*2)*64;   // wave-uniform -> s_load
      #pragma unroll
      for (int k = 0; k < 64; ++k) hacc[k] = fmaf(rlo, wr0[k], hacc[k]);
      const float* wr1 = wr0 + 64;
      #pragma unroll
      for (int k = 0; k < 64; ++k) hacc[k] = fmaf(rhi, wr1[k], hacc[k]);
    }
  }
  float z[16];
  #pragma unroll
  for (int jj = 0; jj < 16; ++jj) z[jj] = bl1[jj];
  #pragma unroll
  for (int k = 0; k < 64; ++k){
    float hk = hacc[k];
    const float* wr = wl1 + k*16;
    #pragma unroll
    for (int jj = 0; jj < 16; ++jj) z[jj] = fmaf(hk, wr[jj], z[jj]);
  }
  float lg[6];
  #pragma unroll
  for (int l = 0; l < 6; ++l) lg[l] = bl2[l];
  #pragma unroll
  for (int jj = 0; jj < 16; ++jj){
    float zj = fmaxf(z[jj], 0.f);
    const float* wr = wl2 + jj*6;
    #pragma unroll
    for (int l = 0; l < 6; ++l) lg[l] = fmaf(zj, wr[l], lg[l]);
  }
  float mx = lg[0];
  #pragma unroll
  for (int l = 1; l < 6; ++l) mx = fmaxf(mx, lg[l]);
  float sum = 0.f;
  #pragma unroll
  for (int l = 0; l < 6; ++l) sum += expf(lg[l] - mx);
  float lse = mx + logf(sum);
  float* op = out + (size_t)i*6;
  #pragma unroll
  for (int l = 0; l < 6; ++l) op[l] = lg[l] - lse;
}

extern "C" void kernel_launch(void* const* d_in, const int* in_sizes, int n_in,
                              void* d_out, int out_size, void* d_ws, size_t ws_size,
                              hipStream_t stream){
  const float* x   = (const float*)d_in[0];
  const int*   ei  = (const int*)d_in[1];
  const float* w1a = (const float*)d_in[2];
  const float* b1a = (const float*)d_in[3];
  const float* g1  = (const float*)d_in[4];
  const float* be1 = (const float*)d_in[5];
  const float* m1  = (const float*)d_in[6];
  const float* v1  = (const float*)d_in[7];
  const float* w1b = (const float*)d_in[8];
  const float* b1b = (const float*)d_in[9];
  const float* w2a = (const float*)d_in[10];
  const float* b2a = (const float*)d_in[11];
  const float* g2  = (const float*)d_in[12];
  const float* be2 = (const float*)d_in[13];
  const float* m2  = (const float*)d_in[14];
  const float* v2  = (const float*)d_in[15];
  const float* w2b = (const float*)d_in[16];
  const float* b2b = (const float*)d_in[17];
  const float* wl1 = (const float*)d_in[18];
  const float* bl1 = (const float*)d_in[19];
  const float* wl2 = (const float*)d_in[20];
  const float* bl2 = (const float*)d_in[21];
  float* out = (float*)d_out;
  int n = in_sizes[0];        // N
  int E = in_sizes[1] / 2;    // edges
  int nb = (n + BW - 1) >> BSH;

  char* ws = (char*)d_ws;
  size_t off = 0;
  auto carve = [&](size_t bytes)->char*{ char* p = ws + off; off += (bytes + 255) & ~(size_t)255; return p; };
  float* a1   = (float*)carve(256*4);
  float* b1v  = (float*)carve(256*4);
  float* c12  = (float*)carve(64*4);
  float* A2   = (float*)carve(64*4);
  float* B2   = (float*)carve(64*4);
  float* W12  = (float*)carve(16384*4);
  float* sorted_p = (float*)carve(256*4);
  int*   perm = (int*)carve(256*4);
  float* AB   = (float*)carve(257*128*4);
  int* gpos   = (int*)carve((size_t)nb*4);
  int* bucket_base = (int*)carve((size_t)nb*4);
  int* rowstart = (int*)carve((size_t)(n+1)*4);
  int* col    = (int*)carve((size_t)E*4);
  uint32_t* binned = (uint32_t*)carve((size_t)nb*SLACK*4);
  unsigned short* t  = (unsigned short*)binned;   // alias: binned dead after sort_bucket
  unsigned short* r2 = (unsigned short*)carve((size_t)n*64*2);

  int nblk = (n + 255) / 256;
  prep_small<<<1, 256, 0, stream>>>(w1a,b1a,g1,be1,m1,v1,b1b,w2a,b2a,g2,be2,m2,v2,
                                    a1,b1v,c12,A2,B2,sorted_p,perm);
  prep_w12<<<64, 256, 0, stream>>>(w1b, w2a, W12);
  build_ab_par<<<128, 256, 0, stream>>>(a1, b1v, W12, c12, perm, AB);
  init_gpos<<<(nb + 255)/256, 256, 0, stream>>>(gpos, nb);
  bin_edges<<<(E + TILE - 1)/TILE, 512, 0, stream>>>(ei, gpos, binned, E, nb);
  scan_buckets<<<1, 512, 0, stream>>>(gpos, bucket_base, rowstart, nb, n, E);
  sort_bucket<<<nb, 512, 0, stream>>>(binned, gpos, bucket_base, rowstart, col, n);
  gin1_pwl<<<((size_t)n*4 + 255)/256, 256, 0, stream>>>(x, rowstart, col, sorted_p, AB, t, n);
  agg8<<<(n + 31)/32, 256, 0, stream>>>(rowstart, col, t, A2, B2, r2, n);
  head_kernel<<<nblk, 256, 0, stream>>>(r2, w2b, b2b, wl1, bl1, wl2, bl2, out, n);
}